// Round 6
// baseline (123.198 us; speedup 1.0000x reference)
//
#include <hip/hip_runtime.h>
#include <hip/hip_bf16.h>
#include <math.h>

#define ENC 512
#define ATT 256
#define NN 1024
#define PP 1024

typedef __attribute__((ext_vector_type(8))) __bf16 bf16x8;
typedef __attribute__((ext_vector_type(4))) float floatx4;
typedef __attribute__((ext_vector_type(2))) float floatx2;

union LdsVec { uint4 u; bf16x8 v; };

// packed fp32->bf16 RNE via v_cvt_pk_bf16_f32 (gfx950)
__device__ __forceinline__ unsigned cvt_pk(float lo, float hi) {
    union { __hip_bfloat162 h; unsigned u; } x;
    x.h = __float22bfloat162_rn(float2{lo, hi});
    return x.u;
}
__device__ __forceinline__ uint4 cvt8(float4 f0, float4 f1) {
    uint4 r;
    r.x = cvt_pk(f0.x, f0.y); r.y = cvt_pk(f0.z, f0.w);
    r.z = cvt_pk(f1.x, f1.y); r.w = cvt_pk(f1.z, f1.w);
    return r;
}

// LDS tile: [rows][64 k] bf16, row stride 128B; 16B granules XOR-swizzled by
// row&7 -> fragment reads (lanes 0-15 = rows, fixed k-granule) spread across
// all 32 banks, <=2-way (free per m136).
__device__ __forceinline__ int t64_off(int row, int k) {
    return row * 64 + ((((k >> 3) ^ row) & 7) << 3) + (k & 7);
}

// ---------------------------------------------------------------------------
// Kernel 1 (grid 4 x 16 x 4):
//  z=0: uT  = (E@We^T+be)^T   z=1: v1T = (D@Wt^T+bt)^T  z=2: v2T = (L@Wl^T+bl)^T
//    outputs TRANSPOSED [a=256][m=1024] so att_exp can stage without scatter.
//  z=3: ET = bf16 transpose of encoder (E^T [512][1024]) for awe_alpha;
//       y==0 blocks also zero srow (workspace is poisoned).
// GEMM: 64x64 tile, BK=64 (8 barrier-iters), 16x16x32 bf16 MFMA, dbuf LDS.
// ---------------------------------------------------------------------------
__global__ __launch_bounds__(256) void mfma_uv(
    const float* __restrict__ E,  const float* __restrict__ We, const float* __restrict__ be,
    const float* __restrict__ D,  const float* __restrict__ Wt, const float* __restrict__ bt,
    const float* __restrict__ Lg, const float* __restrict__ Wl, const float* __restrict__ bl,
    float* __restrict__ uT, float* __restrict__ v1T, float* __restrict__ v2T,
    unsigned short* __restrict__ ET, float* __restrict__ srow)
{
    const int tid = threadIdx.x;

    if (blockIdx.z == 3) {
        if (blockIdx.y == 0) srow[blockIdx.x * 256 + tid] = 0.f;
        // ---- E^T bf16 producer: two 64x64 tiles per block ----
        __shared__ unsigned short T[64][72];           // [k][n], stride 72 u16
        const int k0 = blockIdx.y * 64;
        const int kr = tid >> 2, nc = (tid & 3) * 16;  // read coords
        const int nr = tid >> 2, kc = (tid & 3) * 16;  // write coords
        #pragma unroll
        for (int t = 0; t < 2; ++t) {
            const int n0 = (blockIdx.x * 2 + t) * 64;
            const float* ep = E + (size_t)(k0 + kr) * ENC + n0 + nc;
            float4 a = *(const float4*)(ep + 0),  b = *(const float4*)(ep + 4);
            float4 c = *(const float4*)(ep + 8),  d = *(const float4*)(ep + 12);
            if (t) __syncthreads();                    // prior reads done
            *(uint4*)&T[kr][nc]     = cvt8(a, b);
            *(uint4*)&T[kr][nc + 8] = cvt8(c, d);
            __syncthreads();
            unsigned short tmp[16];
            #pragma unroll
            for (int i = 0; i < 16; ++i) tmp[i] = T[kc + i][nr];
            unsigned short* op = ET + (size_t)(n0 + nr) * PP + k0 + kc;
            *(uint4*)(op)     = *(uint4*)&tmp[0];
            *(uint4*)(op + 8) = *(uint4*)&tmp[8];
        }
        return;
    }

    __shared__ __align__(16) unsigned short As[2][64 * 64];
    __shared__ __align__(16) unsigned short Bs[2][64 * 64];
    const int K = 512;

    const float *A, *B, *bias; float* out;
    if      (blockIdx.z == 0) { A = E;  B = We; bias = be; out = uT;  }
    else if (blockIdx.z == 1) { A = D;  B = Wt; bias = bt; out = v1T; }
    else                      { A = Lg; B = Wl; bias = bl; out = v2T; }

    const int m0 = blockIdx.y * 64, n0 = blockIdx.x * 64;
    const int wv = tid >> 6, lm = tid & 15, lq = (tid >> 4) & 3;
    const int mb = (wv & 1) * 32, nb = (wv >> 1) * 32;
    const int a0l = t64_off(mb + lm,      lq * 8),      a0h = t64_off(mb + lm,      lq * 8 + 32);
    const int a1l = t64_off(mb + 16 + lm, lq * 8),      a1h = t64_off(mb + 16 + lm, lq * 8 + 32);
    const int b0l = t64_off(nb + lm,      lq * 8),      b0h = t64_off(nb + lm,      lq * 8 + 32);
    const int b1l = t64_off(nb + 16 + lm, lq * 8),      b1h = t64_off(nb + 16 + lm, lq * 8 + 32);

    const int row = tid >> 2, kseg = tid & 3;          // stage 2 granules/thread
    const int s0 = t64_off(row, kseg * 8);
    const int s1 = t64_off(row, kseg * 8 + 32);
    const float* Ap = A + (size_t)(m0 + row) * K + kseg * 8;
    const float* Bp = B + (size_t)(n0 + row) * K + kseg * 8;

    floatx4 acc[2][2];
    const floatx4 zero = {0.f, 0.f, 0.f, 0.f};
    acc[0][0] = zero; acc[0][1] = zero; acc[1][0] = zero; acc[1][1] = zero;

    float4 pa0 = *(const float4*)(Ap),      pa1 = *(const float4*)(Ap + 4);
    float4 pa2 = *(const float4*)(Ap + 32), pa3 = *(const float4*)(Ap + 36);
    float4 pb0 = *(const float4*)(Bp),      pb1 = *(const float4*)(Bp + 4);
    float4 pb2 = *(const float4*)(Bp + 32), pb3 = *(const float4*)(Bp + 36);

    for (int k0 = 0; k0 < K; k0 += 64) {
        const int buf = (k0 >> 6) & 1;
        *(uint4*)&As[buf][s0] = cvt8(pa0, pa1);
        *(uint4*)&As[buf][s1] = cvt8(pa2, pa3);
        *(uint4*)&Bs[buf][s0] = cvt8(pb0, pb1);
        *(uint4*)&Bs[buf][s1] = cvt8(pb2, pb3);
        __syncthreads();
        if (k0 + 64 < K) {
            pa0 = *(const float4*)(Ap + k0 + 64); pa1 = *(const float4*)(Ap + k0 + 68);
            pa2 = *(const float4*)(Ap + k0 + 96); pa3 = *(const float4*)(Ap + k0 + 100);
            pb0 = *(const float4*)(Bp + k0 + 64); pb1 = *(const float4*)(Bp + k0 + 68);
            pb2 = *(const float4*)(Bp + k0 + 96); pb3 = *(const float4*)(Bp + k0 + 100);
        }
        LdsVec fa0l, fa0h, fa1l, fa1h, fb0l, fb0h, fb1l, fb1h;
        fa0l.u = *(const uint4*)&As[buf][a0l];  fa0h.u = *(const uint4*)&As[buf][a0h];
        fa1l.u = *(const uint4*)&As[buf][a1l];  fa1h.u = *(const uint4*)&As[buf][a1h];
        fb0l.u = *(const uint4*)&Bs[buf][b0l];  fb0h.u = *(const uint4*)&Bs[buf][b0h];
        fb1l.u = *(const uint4*)&Bs[buf][b1l];  fb1h.u = *(const uint4*)&Bs[buf][b1h];
        acc[0][0] = __builtin_amdgcn_mfma_f32_16x16x32_bf16(fa0l.v, fb0l.v, acc[0][0], 0, 0, 0);
        acc[0][1] = __builtin_amdgcn_mfma_f32_16x16x32_bf16(fa0l.v, fb1l.v, acc[0][1], 0, 0, 0);
        acc[1][0] = __builtin_amdgcn_mfma_f32_16x16x32_bf16(fa1l.v, fb0l.v, acc[1][0], 0, 0, 0);
        acc[1][1] = __builtin_amdgcn_mfma_f32_16x16x32_bf16(fa1l.v, fb1l.v, acc[1][1], 0, 0, 0);
        acc[0][0] = __builtin_amdgcn_mfma_f32_16x16x32_bf16(fa0h.v, fb0h.v, acc[0][0], 0, 0, 0);
        acc[0][1] = __builtin_amdgcn_mfma_f32_16x16x32_bf16(fa0h.v, fb1h.v, acc[0][1], 0, 0, 0);
        acc[1][0] = __builtin_amdgcn_mfma_f32_16x16x32_bf16(fa1h.v, fb0h.v, acc[1][0], 0, 0, 0);
        acc[1][1] = __builtin_amdgcn_mfma_f32_16x16x32_bf16(fa1h.v, fb1h.v, acc[1][1], 0, 0, 0);
    }

    // transposed epilogue: out[a][m], float4 along m (r index)
    #pragma unroll
    for (int s = 0; s < 2; ++s) {
        const int col = n0 + nb + s * 16 + lm;          // a-dim
        const float bsum = bias[col];
        #pragma unroll
        for (int t = 0; t < 2; ++t) {
            const int mbase = m0 + mb + t * 16 + lq * 4;
            float4 o;
            o.x = acc[t][s][0] + bsum; o.y = acc[t][s][1] + bsum;
            o.z = acc[t][s][2] + bsum; o.w = acc[t][s][3] + bsum;
            *(float4*)&out[(size_t)col * NN + mbase] = o;
        }
    }
}

// ---------------------------------------------------------------------------
// Kernel 2: att[n,p] = sum_a relu(uT[a,p]+v1T[a,n]+v2T[a,n]) * Wf[a], then
// exp (no max-sub: |att|<~4 on this data, validated R4), written as fp32 expv
// + bf16 exp_bf, with per-row partial sums atomicAdd'ed into srow[n].
// Tile 64p x 64n, FULL a=256 (8 chunks) -> 256 blocks.  R5's proven
// reg-prefetch + LDS dbuf loop, ONE barrier per chunk (dbuf makes the
// trailing barrier redundant: writes to buf^1 at chunk c+1 are separated
// from the last reads of buf^1 at chunk c-1 by the barrier at chunk c).
// ---------------------------------------------------------------------------
__global__ __launch_bounds__(256) void att_exp(
    const float* __restrict__ uT, const float* __restrict__ v1T,
    const float* __restrict__ v2T, const float* __restrict__ Wf,
    float* __restrict__ expv, unsigned short* __restrict__ exp_bf,
    float* __restrict__ srow)
{
    __shared__ float us[2][32][68];
    __shared__ float vs[2][32][68];
    __shared__ float wfs[256];
    const int tid = threadIdx.x;
    wfs[tid] = Wf[tid];
    const int p0 = blockIdx.x * 64, n0 = blockIdx.y * 64;
    const int rowS = tid >> 3, cS = (tid & 7) * 8;   // staging coords
    const int tx = tid & 15, ty = tid >> 4;          // p = tx*4, n = ty*4

    floatx2 acc[4][2];
    const floatx2 z2 = {0.f, 0.f};
    #pragma unroll
    for (int j = 0; j < 4; ++j) { acc[j][0] = z2; acc[j][1] = z2; }

    // prefetch chunk 0 into registers
    const float* up0 = &uT[(size_t)rowS * NN + p0 + cS];
    const size_t vidx0 = (size_t)rowS * NN + n0 + cS;
    float4 f0 = *(const float4*)up0;
    float4 f1 = *(const float4*)(up0 + 4);
    float4 g0 = *(const float4*)&v1T[vidx0];
    float4 g1 = *(const float4*)&v1T[vidx0 + 4];
    float4 h0 = *(const float4*)&v2T[vidx0];
    float4 h1 = *(const float4*)&v2T[vidx0 + 4];

    for (int ac = 0; ac < 256; ac += 32) {
        const int buf = (ac >> 5) & 1;
        *(float4*)&us[buf][rowS][cS]     = f0;
        *(float4*)&us[buf][rowS][cS + 4] = f1;
        float4 s0, s1;
        s0.x = g0.x + h0.x; s0.y = g0.y + h0.y; s0.z = g0.z + h0.z; s0.w = g0.w + h0.w;
        s1.x = g1.x + h1.x; s1.y = g1.y + h1.y; s1.z = g1.z + h1.z; s1.w = g1.w + h1.w;
        *(float4*)&vs[buf][rowS][cS]     = s0;
        *(float4*)&vs[buf][rowS][cS + 4] = s1;
        __syncthreads();
        if (ac + 32 < 256) {
            const float* upn = &uT[(size_t)(ac + 32 + rowS) * NN + p0 + cS];
            const size_t vn = (size_t)(ac + 32 + rowS) * NN + n0 + cS;
            f0 = *(const float4*)upn;
            f1 = *(const float4*)(upn + 4);
            g0 = *(const float4*)&v1T[vn];
            g1 = *(const float4*)&v1T[vn + 4];
            h0 = *(const float4*)&v2T[vn];
            h1 = *(const float4*)&v2T[vn + 4];
        }
        #pragma unroll
        for (int a4 = 0; a4 < 32; a4 += 4) {
            float4 w4 = *(const float4*)&wfs[ac + a4];
            #pragma unroll
            for (int aa = 0; aa < 4; ++aa) {
                const int a = a4 + aa;
                float4 u4 = *(const float4*)&us[buf][a][tx * 4];
                float4 v4 = *(const float4*)&vs[buf][a][ty * 4];
                const float w = (aa == 0) ? w4.x : (aa == 1) ? w4.y : (aa == 2) ? w4.z : w4.w;
                floatx2 ulo = {u4.x, u4.y}, uhi = {u4.z, u4.w};
                const float vv[4] = {v4.x, v4.y, v4.z, v4.w};
                #pragma unroll
                for (int j = 0; j < 4; ++j) {
                    floatx2 t0 = ulo + vv[j];
                    floatx2 t1 = uhi + vv[j];
                    t0 = __builtin_elementwise_max(t0, z2);
                    t1 = __builtin_elementwise_max(t1, z2);
                    acc[j][0] = t0 * w + acc[j][0];
                    acc[j][1] = t1 * w + acc[j][1];
                }
            }
        }
        __syncthreads();   // all reads of buf done before next chunk's store
    }

    // tail: exp, per-row partial sums, dual-format write
    #pragma unroll
    for (int j = 0; j < 4; ++j) {
        const int n = n0 + ty * 4 + j;
        float4 ex;
        ex.x = __expf(acc[j][0][0]); ex.y = __expf(acc[j][0][1]);
        ex.z = __expf(acc[j][1][0]); ex.w = __expf(acc[j][1][1]);
        float psum = (ex.x + ex.y) + (ex.z + ex.w);
        psum += __shfl_xor(psum, 1, 64);
        psum += __shfl_xor(psum, 2, 64);
        psum += __shfl_xor(psum, 4, 64);
        psum += __shfl_xor(psum, 8, 64);
        if (tx == 0) atomicAdd(&srow[n], psum);
        *(float4*)&expv[(size_t)n * PP + p0 + tx * 4] = ex;
        uint2 pk;
        pk.x = cvt_pk(ex.x, ex.y); pk.y = cvt_pk(ex.z, ex.w);
        *(uint2*)&exp_bf[(size_t)n * PP + p0 + tx * 4] = pk;
    }
}

// ---------------------------------------------------------------------------
// Kernel 3: awe = (exp_bf @ E) / srow  AND  alpha = expv / srow.
// R2/R5's proven mfma_awe GEMM (32m x 64n, BK=64, single barrier per K-step),
// with row-normalization folded into the epilogue; each block also writes its
// disjoint 32x128 fp32 alpha slice (16 KB r+w).
// ---------------------------------------------------------------------------
__global__ __launch_bounds__(256) void awe_alpha(
    const unsigned short* __restrict__ exp_bf, const unsigned short* __restrict__ ET,
    const float* __restrict__ expv, const float* __restrict__ srow,
    float* __restrict__ alpha, float* __restrict__ awe)
{
    __shared__ __align__(16) unsigned short As[2][32 * 64];
    __shared__ __align__(16) unsigned short Bs[2][64 * 64];
    const int tid = threadIdx.x;
    const int K = PP;
    const int m0 = blockIdx.y * 32, n0 = blockIdx.x * 64;
    const int wv = tid >> 6, lm = tid & 15, lq = (tid >> 4) & 3;
    const int mw = (wv & 1) * 16, nw = (wv >> 1) * 32;
    const int aol = t64_off(mw + lm,      lq * 8),  aoh = t64_off(mw + lm,      lq * 8 + 32);
    const int b0l = t64_off(nw + lm,      lq * 8),  b0h = t64_off(nw + lm,      lq * 8 + 32);
    const int b1l = t64_off(nw + 16 + lm, lq * 8),  b1h = t64_off(nw + 16 + lm, lq * 8 + 32);

    const int rowA = tid >> 3, kcA = (tid & 7) * 8;   // one uint4 per thread
    const int rowB = tid >> 2, kcB = (tid & 3) * 8;   // two uint4 per thread
    const int aoff  = t64_off(rowA, kcA);
    const int boff0 = t64_off(rowB, kcB);
    const int boff1 = t64_off(rowB, kcB + 32);
    const unsigned short* Ap = exp_bf + (size_t)(m0 + rowA) * PP + kcA;
    const unsigned short* Bp = ET + (size_t)(n0 + rowB) * PP + kcB;

    floatx4 acc[2];
    const floatx4 zero = {0.f, 0.f, 0.f, 0.f};
    acc[0] = zero; acc[1] = zero;

    uint4 pa  = *(const uint4*)Ap;
    uint4 pb0 = *(const uint4*)Bp;
    uint4 pb1 = *(const uint4*)(Bp + 32);

    for (int k0 = 0; k0 < K; k0 += 64) {
        const int buf = (k0 >> 6) & 1;
        *(uint4*)&As[buf][aoff]  = pa;
        *(uint4*)&Bs[buf][boff0] = pb0;
        *(uint4*)&Bs[buf][boff1] = pb1;
        __syncthreads();
        if (k0 + 64 < K) {
            pa  = *(const uint4*)(Ap + k0 + 64);
            pb0 = *(const uint4*)(Bp + k0 + 64);
            pb1 = *(const uint4*)(Bp + k0 + 96);
        }
        LdsVec fal, fah, fb0l, fb0h, fb1l, fb1h;
        fal.u  = *(const uint4*)&As[buf][aol];
        fah.u  = *(const uint4*)&As[buf][aoh];
        fb0l.u = *(const uint4*)&Bs[buf][b0l];
        fb0h.u = *(const uint4*)&Bs[buf][b0h];
        fb1l.u = *(const uint4*)&Bs[buf][b1l];
        fb1h.u = *(const uint4*)&Bs[buf][b1h];
        acc[0] = __builtin_amdgcn_mfma_f32_16x16x32_bf16(fal.v, fb0l.v, acc[0], 0, 0, 0);
        acc[1] = __builtin_amdgcn_mfma_f32_16x16x32_bf16(fal.v, fb1l.v, acc[1], 0, 0, 0);
        acc[0] = __builtin_amdgcn_mfma_f32_16x16x32_bf16(fah.v, fb0h.v, acc[0], 0, 0, 0);
        acc[1] = __builtin_amdgcn_mfma_f32_16x16x32_bf16(fah.v, fb1h.v, acc[1], 0, 0, 0);
    }

    // epilogue: awe rows scaled by 1/srow
    float invr[4];
    #pragma unroll
    for (int r = 0; r < 4; ++r) invr[r] = 1.0f / srow[m0 + mw + lq * 4 + r];
    #pragma unroll
    for (int s = 0; s < 2; ++s) {
        const int col = n0 + nw + s * 16 + lm;
        #pragma unroll
        for (int r = 0; r < 4; ++r)
            awe[(size_t)(m0 + mw + lq * 4 + r) * ENC + col] = acc[s][r] * invr[r];
    }

    // alpha slice: rows m0..m0+31, cols bx*128..bx*128+127
    {
        const int arow = m0 + (tid >> 3);
        const int acol = blockIdx.x * 128 + (tid & 7) * 16;
        const float inv = 1.0f / srow[arow];
        const float* src = expv + (size_t)arow * PP + acol;
        float* dst = alpha + (size_t)arow * PP + acol;
        #pragma unroll
        for (int q = 0; q < 4; ++q) {
            float4 x = *(const float4*)(src + q * 4);
            x.x *= inv; x.y *= inv; x.z *= inv; x.w *= inv;
            *(float4*)(dst + q * 4) = x;
        }
    }
}

// ---------------------------------------------------------------------------
extern "C" void kernel_launch(void* const* d_in, const int* in_sizes, int n_in,
                              void* d_out, int out_size, void* d_ws, size_t ws_size,
                              hipStream_t stream)
{
    const float* encoder = (const float*)d_in[0];
    const float* dec     = (const float*)d_in[1];
    const float* lang    = (const float*)d_in[2];
    const float* We      = (const float*)d_in[3];
    const float* be      = (const float*)d_in[4];
    const float* Wt      = (const float*)d_in[5];
    const float* bt      = (const float*)d_in[6];
    const float* Wl      = (const float*)d_in[7];
    const float* bl      = (const float*)d_in[8];
    const float* Wf      = (const float*)d_in[9];
    // d_in[10] = bf: uniform over p -> cancels in softmax.

    float* uT   = (float*)d_ws;                  // [256][1024]
    float* v1T  = uT  + ATT * NN;                // [256][1024]
    float* v2T  = v1T + ATT * NN;                // [256][1024]
    float* expv = v2T + ATT * NN;                // [1024][1024] fp32
    float* srow = expv + (size_t)NN * PP;        // [1024]
    unsigned short* exp_bf = (unsigned short*)(srow + NN);   // [1024][1024] bf16
    unsigned short* ET     = exp_bf + (size_t)NN * PP;       // [512][1024]

    float* awe   = (float*)d_out;                // (1024, 512)
    float* alpha = (float*)d_out + NN * ENC;     // (1024, 1024)

    mfma_uv<<<dim3(4, 16, 4), 256, 0, stream>>>(
        encoder, We, be, dec, Wt, bt, lang, Wl, bl, uT, v1T, v2T, ET, srow);
    att_exp<<<dim3(PP / 64, NN / 64), 256, 0, stream>>>(
        uT, v1T, v2T, Wf, expv, exp_bf, srow);
    awe_alpha<<<dim3(ENC / 64, NN / 32), 256, 0, stream>>>(
        exp_bf, ET, expv, srow, alpha, awe);
}

// Round 7
// 119.307 us; speedup vs baseline: 1.0326x; 1.0326x over previous
//
#include <hip/hip_runtime.h>
#include <hip/hip_bf16.h>
#include <math.h>

#define ENC 512
#define ATT 256
#define NN 1024
#define PP 1024

typedef __attribute__((ext_vector_type(8))) __bf16 bf16x8;
typedef __attribute__((ext_vector_type(4))) float floatx4;
typedef __attribute__((ext_vector_type(2))) float floatx2;

union LdsVec { uint4 u; bf16x8 v; };

// packed fp32->bf16 RNE via v_cvt_pk_bf16_f32 (gfx950)
__device__ __forceinline__ unsigned cvt_pk(float lo, float hi) {
    union { __hip_bfloat162 h; unsigned u; } x;
    x.h = __float22bfloat162_rn(float2{lo, hi});
    return x.u;
}
__device__ __forceinline__ uint4 cvt8(float4 f0, float4 f1) {
    uint4 r;
    r.x = cvt_pk(f0.x, f0.y); r.y = cvt_pk(f0.z, f0.w);
    r.z = cvt_pk(f1.x, f1.y); r.w = cvt_pk(f1.z, f1.w);
    return r;
}

// LDS tile: [rows][64 k] bf16, row stride 128B; 16B granules XOR-swizzled by
// row&7 -> fragment reads (lanes 0-15 = rows, fixed k-granule) spread across
// all 32 banks, <=2-way (free per m136).
__device__ __forceinline__ int t64_off(int row, int k) {
    return row * 64 + ((((k >> 3) ^ row) & 7) << 3) + (k & 7);
}

// ---------------------------------------------------------------------------
// Kernel 1 (grid 4 x 16 x 4):
//  z=0: uT  = (E@We^T+be)^T   z=1: v1T = (D@Wt^T+bt)^T  z=2: v2T = (L@Wl^T+bl)^T
//    outputs TRANSPOSED [a=256][m=1024] so att_fused can stage without scatter.
//  z=3: ET = bf16 transpose of encoder (E^T [512][1024]) for mfma_awe.
// GEMM: 64x64 tile, BK=64 (8 barrier-iters, ONE barrier each), dbuf LDS.
// ---------------------------------------------------------------------------
__global__ __launch_bounds__(256) void mfma_uv(
    const float* __restrict__ E,  const float* __restrict__ We, const float* __restrict__ be,
    const float* __restrict__ D,  const float* __restrict__ Wt, const float* __restrict__ bt,
    const float* __restrict__ Lg, const float* __restrict__ Wl, const float* __restrict__ bl,
    float* __restrict__ uT, float* __restrict__ v1T, float* __restrict__ v2T,
    unsigned short* __restrict__ ET)
{
    const int tid = threadIdx.x;

    if (blockIdx.z == 3) {
        // ---- E^T bf16 producer: two 64x64 tiles per block ----
        __shared__ unsigned short T[64][72];           // [k][n], stride 72 u16
        const int k0 = blockIdx.y * 64;
        const int kr = tid >> 2, nc = (tid & 3) * 16;  // read coords
        const int nr = tid >> 2, kc = (tid & 3) * 16;  // write coords
        #pragma unroll
        for (int t = 0; t < 2; ++t) {
            const int n0 = (blockIdx.x * 2 + t) * 64;
            const float* ep = E + (size_t)(k0 + kr) * ENC + n0 + nc;
            float4 a = *(const float4*)(ep + 0),  b = *(const float4*)(ep + 4);
            float4 c = *(const float4*)(ep + 8),  d = *(const float4*)(ep + 12);
            if (t) __syncthreads();                    // prior reads done
            *(uint4*)&T[kr][nc]     = cvt8(a, b);
            *(uint4*)&T[kr][nc + 8] = cvt8(c, d);
            __syncthreads();
            unsigned short tmp[16];
            #pragma unroll
            for (int i = 0; i < 16; ++i) tmp[i] = T[kc + i][nr];
            unsigned short* op = ET + (size_t)(n0 + nr) * PP + k0 + kc;
            *(uint4*)(op)     = *(uint4*)&tmp[0];
            *(uint4*)(op + 8) = *(uint4*)&tmp[8];
        }
        return;
    }

    __shared__ __align__(16) unsigned short As[2][64 * 64];
    __shared__ __align__(16) unsigned short Bs[2][64 * 64];
    const int K = 512;

    const float *A, *B, *bias; float* out;
    if      (blockIdx.z == 0) { A = E;  B = We; bias = be; out = uT;  }
    else if (blockIdx.z == 1) { A = D;  B = Wt; bias = bt; out = v1T; }
    else                      { A = Lg; B = Wl; bias = bl; out = v2T; }

    const int m0 = blockIdx.y * 64, n0 = blockIdx.x * 64;
    const int wv = tid >> 6, lm = tid & 15, lq = (tid >> 4) & 3;
    const int mb = (wv & 1) * 32, nb = (wv >> 1) * 32;
    const int a0l = t64_off(mb + lm,      lq * 8),      a0h = t64_off(mb + lm,      lq * 8 + 32);
    const int a1l = t64_off(mb + 16 + lm, lq * 8),      a1h = t64_off(mb + 16 + lm, lq * 8 + 32);
    const int b0l = t64_off(nb + lm,      lq * 8),      b0h = t64_off(nb + lm,      lq * 8 + 32);
    const int b1l = t64_off(nb + 16 + lm, lq * 8),      b1h = t64_off(nb + 16 + lm, lq * 8 + 32);

    const int row = tid >> 2, kseg = tid & 3;          // stage 2 granules/thread
    const int s0 = t64_off(row, kseg * 8);
    const int s1 = t64_off(row, kseg * 8 + 32);
    const float* Ap = A + (size_t)(m0 + row) * K + kseg * 8;
    const float* Bp = B + (size_t)(n0 + row) * K + kseg * 8;

    floatx4 acc[2][2];
    const floatx4 zero = {0.f, 0.f, 0.f, 0.f};
    acc[0][0] = zero; acc[0][1] = zero; acc[1][0] = zero; acc[1][1] = zero;

    float4 pa0 = *(const float4*)(Ap),      pa1 = *(const float4*)(Ap + 4);
    float4 pa2 = *(const float4*)(Ap + 32), pa3 = *(const float4*)(Ap + 36);
    float4 pb0 = *(const float4*)(Bp),      pb1 = *(const float4*)(Bp + 4);
    float4 pb2 = *(const float4*)(Bp + 32), pb3 = *(const float4*)(Bp + 36);

    for (int k0 = 0; k0 < K; k0 += 64) {
        const int buf = (k0 >> 6) & 1;
        *(uint4*)&As[buf][s0] = cvt8(pa0, pa1);
        *(uint4*)&As[buf][s1] = cvt8(pa2, pa3);
        *(uint4*)&Bs[buf][s0] = cvt8(pb0, pb1);
        *(uint4*)&Bs[buf][s1] = cvt8(pb2, pb3);
        __syncthreads();
        if (k0 + 64 < K) {
            pa0 = *(const float4*)(Ap + k0 + 64); pa1 = *(const float4*)(Ap + k0 + 68);
            pa2 = *(const float4*)(Ap + k0 + 96); pa3 = *(const float4*)(Ap + k0 + 100);
            pb0 = *(const float4*)(Bp + k0 + 64); pb1 = *(const float4*)(Bp + k0 + 68);
            pb2 = *(const float4*)(Bp + k0 + 96); pb3 = *(const float4*)(Bp + k0 + 100);
        }
        LdsVec fa0l, fa0h, fa1l, fa1h, fb0l, fb0h, fb1l, fb1h;
        fa0l.u = *(const uint4*)&As[buf][a0l];  fa0h.u = *(const uint4*)&As[buf][a0h];
        fa1l.u = *(const uint4*)&As[buf][a1l];  fa1h.u = *(const uint4*)&As[buf][a1h];
        fb0l.u = *(const uint4*)&Bs[buf][b0l];  fb0h.u = *(const uint4*)&Bs[buf][b0h];
        fb1l.u = *(const uint4*)&Bs[buf][b1l];  fb1h.u = *(const uint4*)&Bs[buf][b1h];
        acc[0][0] = __builtin_amdgcn_mfma_f32_16x16x32_bf16(fa0l.v, fb0l.v, acc[0][0], 0, 0, 0);
        acc[0][1] = __builtin_amdgcn_mfma_f32_16x16x32_bf16(fa0l.v, fb1l.v, acc[0][1], 0, 0, 0);
        acc[1][0] = __builtin_amdgcn_mfma_f32_16x16x32_bf16(fa1l.v, fb0l.v, acc[1][0], 0, 0, 0);
        acc[1][1] = __builtin_amdgcn_mfma_f32_16x16x32_bf16(fa1l.v, fb1l.v, acc[1][1], 0, 0, 0);
        acc[0][0] = __builtin_amdgcn_mfma_f32_16x16x32_bf16(fa0h.v, fb0h.v, acc[0][0], 0, 0, 0);
        acc[0][1] = __builtin_amdgcn_mfma_f32_16x16x32_bf16(fa0h.v, fb1h.v, acc[0][1], 0, 0, 0);
        acc[1][0] = __builtin_amdgcn_mfma_f32_16x16x32_bf16(fa1h.v, fb0h.v, acc[1][0], 0, 0, 0);
        acc[1][1] = __builtin_amdgcn_mfma_f32_16x16x32_bf16(fa1h.v, fb1h.v, acc[1][1], 0, 0, 0);
    }

    // transposed epilogue: out[a][m], float4 along m (r index)
    #pragma unroll
    for (int s = 0; s < 2; ++s) {
        const int col = n0 + nb + s * 16 + lm;          // a-dim
        const float bsum = bias[col];
        #pragma unroll
        for (int t = 0; t < 2; ++t) {
            const int mbase = m0 + mb + t * 16 + lq * 4;
            float4 o;
            o.x = acc[t][s][0] + bsum; o.y = acc[t][s][1] + bsum;
            o.z = acc[t][s][2] + bsum; o.w = acc[t][s][3] + bsum;
            *(float4*)&out[(size_t)col * NN + mbase] = o;
        }
    }
}

// ---------------------------------------------------------------------------
// Kernel 2: att[n,p] = sum_a relu(uT[a,p] + v1T[a,n] + v2T[a,n]) * Wf[a]
// Tile 64p x 64n, thread 4p x 4n. z splits a-range in half -> 512 blocks
// (2 blocks/CU); partials summed in softmax.
// Reg-prefetch + LDS dbuf, ONE barrier per chunk: store(c+1) targets buf^1,
// whose last reads were in compute(c-1), fenced by barrier(c).
// ---------------------------------------------------------------------------
__global__ __launch_bounds__(256) void att_fused(
    const float* __restrict__ uT, const float* __restrict__ v1T,
    const float* __restrict__ v2T,
    const float* __restrict__ Wf, float* __restrict__ att_part)
{
    __shared__ float us[2][32][68];
    __shared__ float vs[2][32][68];
    __shared__ float wfs[128];
    const int tid = threadIdx.x;
    const int z = blockIdx.z;
    if (tid < 128) wfs[tid] = Wf[z * 128 + tid];
    const int p0 = blockIdx.x * 64, n0 = blockIdx.y * 64;
    const int rowS = tid >> 3, cS = (tid & 7) * 8;   // staging coords
    const int tx = tid & 15, ty = tid >> 4;          // p = tx*4, n = ty*4

    floatx2 acc[4][2];
    const floatx2 z2 = {0.f, 0.f};
    #pragma unroll
    for (int j = 0; j < 4; ++j) { acc[j][0] = z2; acc[j][1] = z2; }

    const int abase = z * 128;

    // prefetch chunk 0 into registers
    const float* up0 = &uT[(size_t)(abase + rowS) * NN + p0 + cS];
    const size_t vidx0 = (size_t)(abase + rowS) * NN + n0 + cS;
    float4 f0 = *(const float4*)up0;
    float4 f1 = *(const float4*)(up0 + 4);
    float4 g0 = *(const float4*)&v1T[vidx0];
    float4 g1 = *(const float4*)&v1T[vidx0 + 4];
    float4 h0 = *(const float4*)&v2T[vidx0];
    float4 h1 = *(const float4*)&v2T[vidx0 + 4];

    for (int ac = 0; ac < 128; ac += 32) {
        const int buf = (ac >> 5) & 1;
        // store staged registers (v1+v2 summed in-register)
        *(float4*)&us[buf][rowS][cS]     = f0;
        *(float4*)&us[buf][rowS][cS + 4] = f1;
        float4 s0, s1;
        s0.x = g0.x + h0.x; s0.y = g0.y + h0.y; s0.z = g0.z + h0.z; s0.w = g0.w + h0.w;
        s1.x = g1.x + h1.x; s1.y = g1.y + h1.y; s1.z = g1.z + h1.z; s1.w = g1.w + h1.w;
        *(float4*)&vs[buf][rowS][cS]     = s0;
        *(float4*)&vs[buf][rowS][cS + 4] = s1;
        __syncthreads();
        if (ac + 32 < 128) {
            const float* upn = &uT[(size_t)(abase + ac + 32 + rowS) * NN + p0 + cS];
            const size_t vn = (size_t)(abase + ac + 32 + rowS) * NN + n0 + cS;
            f0 = *(const float4*)upn;
            f1 = *(const float4*)(upn + 4);
            g0 = *(const float4*)&v1T[vn];
            g1 = *(const float4*)&v1T[vn + 4];
            h0 = *(const float4*)&v2T[vn];
            h1 = *(const float4*)&v2T[vn + 4];
        }
        #pragma unroll
        for (int a4 = 0; a4 < 32; a4 += 4) {
            float4 w4 = *(const float4*)&wfs[ac + a4];
            #pragma unroll
            for (int aa = 0; aa < 4; ++aa) {
                const int a = a4 + aa;
                float4 u4 = *(const float4*)&us[buf][a][tx * 4];
                float4 v4 = *(const float4*)&vs[buf][a][ty * 4];
                const float w = (aa == 0) ? w4.x : (aa == 1) ? w4.y : (aa == 2) ? w4.z : w4.w;
                floatx2 ulo = {u4.x, u4.y}, uhi = {u4.z, u4.w};
                const float vv[4] = {v4.x, v4.y, v4.z, v4.w};
                #pragma unroll
                for (int j = 0; j < 4; ++j) {
                    floatx2 t0 = ulo + vv[j];
                    floatx2 t1 = uhi + vv[j];
                    t0 = __builtin_elementwise_max(t0, z2);
                    t1 = __builtin_elementwise_max(t1, z2);
                    acc[j][0] = t0 * w + acc[j][0];
                    acc[j][1] = t1 * w + acc[j][1];
                }
            }
        }
        // no trailing barrier: dbuf + barrier(c+1) provide the fence
    }

    float* outp = att_part + (size_t)z * NN * PP;
    #pragma unroll
    for (int j = 0; j < 4; ++j) {
        float4 o;
        o.x = acc[j][0].x; o.y = acc[j][0].y; o.z = acc[j][1].x; o.w = acc[j][1].y;
        *(float4*)&outp[(size_t)(n0 + ty * 4 + j) * PP + p0 + tx * 4] = o;
    }
}

// ---------------------------------------------------------------------------
// Kernel 3: softmax over p of (att_part0 + att_part1); writes fp32 alpha to
// d_out AND bf16 alpha to ws for mfma_awe.  Wave-per-row, no barriers.
// ---------------------------------------------------------------------------
__global__ __launch_bounds__(256) void softmax_rows(
    const float* __restrict__ att_part, float* __restrict__ alpha,
    unsigned short* __restrict__ alpha_bf)
{
    const int wv = threadIdx.x >> 6, lane = threadIdx.x & 63;
    const int n = blockIdx.x * 4 + wv;
    const float* r0 = att_part + (size_t)n * PP;
    const float* r1 = att_part + (size_t)NN * PP + (size_t)n * PP;

    float4 x[4];
    #pragma unroll
    for (int i = 0; i < 4; ++i) {
        float4 a = *(const float4*)&r0[i * 256 + lane * 4];
        float4 b = *(const float4*)&r1[i * 256 + lane * 4];
        x[i].x = a.x + b.x; x[i].y = a.y + b.y; x[i].z = a.z + b.z; x[i].w = a.w + b.w;
    }

    float m = -1e30f;
    #pragma unroll
    for (int i = 0; i < 4; ++i)
        m = fmaxf(m, fmaxf(fmaxf(x[i].x, x[i].y), fmaxf(x[i].z, x[i].w)));
    #pragma unroll
    for (int off = 32; off > 0; off >>= 1) m = fmaxf(m, __shfl_xor(m, off, 64));

    float s = 0.f;
    #pragma unroll
    for (int i = 0; i < 4; ++i) {
        x[i].x = __expf(x[i].x - m); x[i].y = __expf(x[i].y - m);
        x[i].z = __expf(x[i].z - m); x[i].w = __expf(x[i].w - m);
        s += x[i].x + x[i].y + x[i].z + x[i].w;
    }
    #pragma unroll
    for (int off = 32; off > 0; off >>= 1) s += __shfl_xor(s, off, 64);
    const float inv = 1.0f / s;

    float* ar = alpha + (size_t)n * PP;
    unsigned short* br = alpha_bf + (size_t)n * PP;
    #pragma unroll
    for (int i = 0; i < 4; ++i) {
        x[i].x *= inv; x[i].y *= inv; x[i].z *= inv; x[i].w *= inv;
        *(float4*)&ar[i * 256 + lane * 4] = x[i];
        uint2 pk;
        pk.x = cvt_pk(x[i].x, x[i].y);
        pk.y = cvt_pk(x[i].z, x[i].w);
        *(uint2*)&br[i * 256 + lane * 4] = pk;
    }
}

// ---------------------------------------------------------------------------
// Kernel 4: awe = alpha @ E, both operands pre-converted bf16 (alpha_bf, ET).
// Tile 32m x 64n, BK=64 (16 K-steps, ONE barrier each — R2's proven form;
// dbuf fences the cross-iteration LDS hazard), 256 blocks, pure copy staging.
// ---------------------------------------------------------------------------
__global__ __launch_bounds__(256) void mfma_awe(
    const unsigned short* __restrict__ alpha_bf,
    const unsigned short* __restrict__ ET, float* __restrict__ awe)
{
    __shared__ __align__(16) unsigned short As[2][32 * 64];
    __shared__ __align__(16) unsigned short Bs[2][64 * 64];
    const int tid = threadIdx.x;
    const int K = PP;
    const int m0 = blockIdx.y * 32, n0 = blockIdx.x * 64;
    const int wv = tid >> 6, lm = tid & 15, lq = (tid >> 4) & 3;
    const int mw = (wv & 1) * 16, nw = (wv >> 1) * 32;
    const int aol = t64_off(mw + lm,      lq * 8),  aoh = t64_off(mw + lm,      lq * 8 + 32);
    const int b0l = t64_off(nw + lm,      lq * 8),  b0h = t64_off(nw + lm,      lq * 8 + 32);
    const int b1l = t64_off(nw + 16 + lm, lq * 8),  b1h = t64_off(nw + 16 + lm, lq * 8 + 32);

    const int rowA = tid >> 3, kcA = (tid & 7) * 8;   // one uint4 per thread (full 32x64)
    const int rowB = tid >> 2, kcB = (tid & 3) * 8;   // two uint4 per thread
    const int aoff  = t64_off(rowA, kcA);
    const int boff0 = t64_off(rowB, kcB);
    const int boff1 = t64_off(rowB, kcB + 32);
    const unsigned short* Ap = alpha_bf + (size_t)(m0 + rowA) * PP + kcA;
    const unsigned short* Bp = ET + (size_t)(n0 + rowB) * PP + kcB;

    floatx4 acc[2];
    const floatx4 zero = {0.f, 0.f, 0.f, 0.f};
    acc[0] = zero; acc[1] = zero;

    uint4 pa  = *(const uint4*)Ap;
    uint4 pb0 = *(const uint4*)Bp;
    uint4 pb1 = *(const uint4*)(Bp + 32);

    for (int k0 = 0; k0 < K; k0 += 64) {
        const int buf = (k0 >> 6) & 1;
        *(uint4*)&As[buf][aoff]  = pa;
        *(uint4*)&Bs[buf][boff0] = pb0;
        *(uint4*)&Bs[buf][boff1] = pb1;
        __syncthreads();
        if (k0 + 64 < K) {
            pa  = *(const uint4*)(Ap + k0 + 64);
            pb0 = *(const uint4*)(Bp + k0 + 64);
            pb1 = *(const uint4*)(Bp + k0 + 96);
        }
        LdsVec fal, fah, fb0l, fb0h, fb1l, fb1h;
        fal.u  = *(const uint4*)&As[buf][aol];
        fah.u  = *(const uint4*)&As[buf][aoh];
        fb0l.u = *(const uint4*)&Bs[buf][b0l];
        fb0h.u = *(const uint4*)&Bs[buf][b0h];
        fb1l.u = *(const uint4*)&Bs[buf][b1l];
        fb1h.u = *(const uint4*)&Bs[buf][b1h];
        acc[0] = __builtin_amdgcn_mfma_f32_16x16x32_bf16(fal.v, fb0l.v, acc[0], 0, 0, 0);
        acc[1] = __builtin_amdgcn_mfma_f32_16x16x32_bf16(fal.v, fb1l.v, acc[1], 0, 0, 0);
        acc[0] = __builtin_amdgcn_mfma_f32_16x16x32_bf16(fah.v, fb0h.v, acc[0], 0, 0, 0);
        acc[1] = __builtin_amdgcn_mfma_f32_16x16x32_bf16(fah.v, fb1h.v, acc[1], 0, 0, 0);
        // no trailing barrier: dbuf + next iteration's barrier fence the hazard
    }

    #pragma unroll
    for (int s = 0; s < 2; ++s) {
        const int col = n0 + nw + s * 16 + lm;
        #pragma unroll
        for (int r = 0; r < 4; ++r)
            awe[(size_t)(m0 + mw + lq * 4 + r) * ENC + col] = acc[s][r];
    }
}

// ---------------------------------------------------------------------------
extern "C" void kernel_launch(void* const* d_in, const int* in_sizes, int n_in,
                              void* d_out, int out_size, void* d_ws, size_t ws_size,
                              hipStream_t stream)
{
    const float* encoder = (const float*)d_in[0];
    const float* dec     = (const float*)d_in[1];
    const float* lang    = (const float*)d_in[2];
    const float* We      = (const float*)d_in[3];
    const float* be      = (const float*)d_in[4];
    const float* Wt      = (const float*)d_in[5];
    const float* bt      = (const float*)d_in[6];
    const float* Wl      = (const float*)d_in[7];
    const float* bl      = (const float*)d_in[8];
    const float* Wf      = (const float*)d_in[9];
    // d_in[10] = bf: uniform over p -> cancels in softmax.

    float* uT   = (float*)d_ws;                  // [256][1024]
    float* v1T  = uT  + ATT * NN;                // [256][1024]
    float* v2T  = v1T + ATT * NN;                // [256][1024]
    float* attp = v2T + ATT * NN;                // [2][1024][1024]
    unsigned short* alpha_bf = (unsigned short*)(attp + 2 * (size_t)NN * PP);  // [1024][1024]
    unsigned short* ET       = alpha_bf + (size_t)NN * PP;                     // [512][1024]

    float* awe   = (float*)d_out;                // (1024, 512)
    float* alpha = (float*)d_out + NN * ENC;     // (1024, 1024)

    mfma_uv<<<dim3(4, 16, 4), 256, 0, stream>>>(
        encoder, We, be, dec, Wt, bt, lang, Wl, bl, uT, v1T, v2T, ET);
    att_fused<<<dim3(PP / 64, NN / 64, 2), 256, 0, stream>>>(uT, v1T, v2T, Wf, attp);
    softmax_rows<<<dim3(NN / 4), 256, 0, stream>>>(attp, alpha, alpha_bf);
    mfma_awe<<<dim3(ENC / 64, NN / 32), 256, 0, stream>>>(alpha_bf, ET, awe);
}

// Round 8
// 116.861 us; speedup vs baseline: 1.0542x; 1.0209x over previous
//
#include <hip/hip_runtime.h>
#include <hip/hip_bf16.h>
#include <math.h>

#define ENC 512
#define ATT 256
#define NN 1024
#define PP 1024

typedef __attribute__((ext_vector_type(8))) __bf16 bf16x8;
typedef __attribute__((ext_vector_type(4))) float floatx4;
typedef __attribute__((ext_vector_type(2))) float floatx2;

union LdsVec { uint4 u; bf16x8 v; };

// packed fp32->bf16 RNE via v_cvt_pk_bf16_f32 (gfx950)
__device__ __forceinline__ unsigned cvt_pk(float lo, float hi) {
    union { __hip_bfloat162 h; unsigned u; } x;
    x.h = __float22bfloat162_rn(float2{lo, hi});
    return x.u;
}
__device__ __forceinline__ uint4 cvt8(float4 f0, float4 f1) {
    uint4 r;
    r.x = cvt_pk(f0.x, f0.y); r.y = cvt_pk(f0.z, f0.w);
    r.z = cvt_pk(f1.x, f1.y); r.w = cvt_pk(f1.z, f1.w);
    return r;
}

// LDS tile, 128-k row stride bf16 (256B/row); 16B granules XOR-swizzled by
// row&7 within each 8-granule half -> fragment reads (lanes 0-15 = rows,
// fixed k-granule) spread across all 32 banks, <=2-way (free per m136).
__device__ __forceinline__ int t128_off(int row, int k) {
    const int g = k >> 3;
    return row * 128 + (((g & 8) | ((g ^ row) & 7)) << 3) + (k & 7);
}

// ---------------------------------------------------------------------------
// Kernel 1 (grid 4 x 16 x 4):
//  z=0: uT  = (E@We^T+be)^T   z=1: v1T = (D@Wt^T+bt)^T  z=2: v2T = (L@Wl^T+bl)^T
//    outputs TRANSPOSED [a=256][m=1024] so att_fused can stage without scatter.
//  z=3: ET = bf16 transpose of encoder (E^T [512][1024]) for mfma_awe.
// GEMM: 64x64 tile, BK=128 (4 K-steps, ONE barrier each), dbuf LDS (64 KB).
// ---------------------------------------------------------------------------
__global__ __launch_bounds__(256) void mfma_uv(
    const float* __restrict__ E,  const float* __restrict__ We, const float* __restrict__ be,
    const float* __restrict__ D,  const float* __restrict__ Wt, const float* __restrict__ bt,
    const float* __restrict__ Lg, const float* __restrict__ Wl, const float* __restrict__ bl,
    float* __restrict__ uT, float* __restrict__ v1T, float* __restrict__ v2T,
    unsigned short* __restrict__ ET)
{
    const int tid = threadIdx.x;

    if (blockIdx.z == 3) {
        // ---- E^T bf16 producer: two 64x64 tiles per block ----
        __shared__ unsigned short T[64][72];           // [k][n], stride 72 u16
        const int k0 = blockIdx.y * 64;
        const int kr = tid >> 2, nc = (tid & 3) * 16;  // read coords
        const int nr = tid >> 2, kc = (tid & 3) * 16;  // write coords
        #pragma unroll
        for (int t = 0; t < 2; ++t) {
            const int n0 = (blockIdx.x * 2 + t) * 64;
            const float* ep = E + (size_t)(k0 + kr) * ENC + n0 + nc;
            float4 a = *(const float4*)(ep + 0),  b = *(const float4*)(ep + 4);
            float4 c = *(const float4*)(ep + 8),  d = *(const float4*)(ep + 12);
            if (t) __syncthreads();                    // prior reads done
            *(uint4*)&T[kr][nc]     = cvt8(a, b);
            *(uint4*)&T[kr][nc + 8] = cvt8(c, d);
            __syncthreads();
            unsigned short tmp[16];
            #pragma unroll
            for (int i = 0; i < 16; ++i) tmp[i] = T[kc + i][nr];
            unsigned short* op = ET + (size_t)(n0 + nr) * PP + k0 + kc;
            *(uint4*)(op)     = *(uint4*)&tmp[0];
            *(uint4*)(op + 8) = *(uint4*)&tmp[8];
        }
        return;
    }

    __shared__ __align__(16) unsigned short As[2][64 * 128];
    __shared__ __align__(16) unsigned short Bs[2][64 * 128];
    const int K = 512;

    const float *A, *B, *bias; float* out;
    if      (blockIdx.z == 0) { A = E;  B = We; bias = be; out = uT;  }
    else if (blockIdx.z == 1) { A = D;  B = Wt; bias = bt; out = v1T; }
    else                      { A = Lg; B = Wl; bias = bl; out = v2T; }

    const int m0 = blockIdx.y * 64, n0 = blockIdx.x * 64;
    const int wv = tid >> 6, lm = tid & 15, lq = (tid >> 4) & 3;
    const int mb = (wv & 1) * 32, nb = (wv >> 1) * 32;
    int aoffs[2][4], boffs[2][4];
    #pragma unroll
    for (int ks = 0; ks < 4; ++ks) {
        aoffs[0][ks] = t128_off(mb + lm,      lq * 8 + ks * 32);
        aoffs[1][ks] = t128_off(mb + 16 + lm, lq * 8 + ks * 32);
        boffs[0][ks] = t128_off(nb + lm,      lq * 8 + ks * 32);
        boffs[1][ks] = t128_off(nb + 16 + lm, lq * 8 + ks * 32);
    }

    const int row = tid >> 2, kseg = (tid & 3) * 8;    // stage 4 granules/thread
    int soffs[4];
    #pragma unroll
    for (int j = 0; j < 4; ++j) soffs[j] = t128_off(row, kseg + j * 32);
    const float* Ap = A + (size_t)(m0 + row) * K + kseg;
    const float* Bp = B + (size_t)(n0 + row) * K + kseg;

    floatx4 acc[2][2];
    const floatx4 zero = {0.f, 0.f, 0.f, 0.f};
    acc[0][0] = zero; acc[0][1] = zero; acc[1][0] = zero; acc[1][1] = zero;

    float4 pa[8], pb[8];
    #pragma unroll
    for (int j = 0; j < 4; ++j) {
        pa[2 * j]     = *(const float4*)(Ap + j * 32);
        pa[2 * j + 1] = *(const float4*)(Ap + j * 32 + 4);
        pb[2 * j]     = *(const float4*)(Bp + j * 32);
        pb[2 * j + 1] = *(const float4*)(Bp + j * 32 + 4);
    }

    for (int k0 = 0; k0 < K; k0 += 128) {
        const int buf = (k0 >> 7) & 1;
        #pragma unroll
        for (int j = 0; j < 4; ++j) {
            *(uint4*)&As[buf][soffs[j]] = cvt8(pa[2 * j], pa[2 * j + 1]);
            *(uint4*)&Bs[buf][soffs[j]] = cvt8(pb[2 * j], pb[2 * j + 1]);
        }
        __syncthreads();
        if (k0 + 128 < K) {
            #pragma unroll
            for (int j = 0; j < 4; ++j) {
                pa[2 * j]     = *(const float4*)(Ap + k0 + 128 + j * 32);
                pa[2 * j + 1] = *(const float4*)(Ap + k0 + 128 + j * 32 + 4);
                pb[2 * j]     = *(const float4*)(Bp + k0 + 128 + j * 32);
                pb[2 * j + 1] = *(const float4*)(Bp + k0 + 128 + j * 32 + 4);
            }
        }
        #pragma unroll
        for (int ks = 0; ks < 4; ++ks) {
            LdsVec fa0, fa1, fb0, fb1;
            fa0.u = *(const uint4*)&As[buf][aoffs[0][ks]];
            fa1.u = *(const uint4*)&As[buf][aoffs[1][ks]];
            fb0.u = *(const uint4*)&Bs[buf][boffs[0][ks]];
            fb1.u = *(const uint4*)&Bs[buf][boffs[1][ks]];
            acc[0][0] = __builtin_amdgcn_mfma_f32_16x16x32_bf16(fa0.v, fb0.v, acc[0][0], 0, 0, 0);
            acc[0][1] = __builtin_amdgcn_mfma_f32_16x16x32_bf16(fa0.v, fb1.v, acc[0][1], 0, 0, 0);
            acc[1][0] = __builtin_amdgcn_mfma_f32_16x16x32_bf16(fa1.v, fb0.v, acc[1][0], 0, 0, 0);
            acc[1][1] = __builtin_amdgcn_mfma_f32_16x16x32_bf16(fa1.v, fb1.v, acc[1][1], 0, 0, 0);
        }
        // no trailing barrier: dbuf + next iteration's barrier fence the hazard
    }

    // transposed epilogue: out[a][m], float4 along m (r index)
    #pragma unroll
    for (int s = 0; s < 2; ++s) {
        const int col = n0 + nb + s * 16 + lm;          // a-dim
        const float bsum = bias[col];
        #pragma unroll
        for (int t = 0; t < 2; ++t) {
            const int mbase = m0 + mb + t * 16 + lq * 4;
            float4 o;
            o.x = acc[t][s][0] + bsum; o.y = acc[t][s][1] + bsum;
            o.z = acc[t][s][2] + bsum; o.w = acc[t][s][3] + bsum;
            *(float4*)&out[(size_t)col * NN + mbase] = o;
        }
    }
}

// ---------------------------------------------------------------------------
// Kernel 2: att[n,p] = sum_a relu(uT[a,p] + v1T[a,n] + v2T[a,n]) * Wf[a]
// Tile 64p x 64n, thread 4p x 4n. z splits a-range in half -> 512 blocks
// (2 blocks/CU); partials summed in softmax.
// Reg-prefetch + LDS dbuf, ONE barrier per chunk.
// ---------------------------------------------------------------------------
__global__ __launch_bounds__(256) void att_fused(
    const float* __restrict__ uT, const float* __restrict__ v1T,
    const float* __restrict__ v2T,
    const float* __restrict__ Wf, float* __restrict__ att_part)
{
    __shared__ float us[2][32][68];
    __shared__ float vs[2][32][68];
    __shared__ float wfs[128];
    const int tid = threadIdx.x;
    const int z = blockIdx.z;
    if (tid < 128) wfs[tid] = Wf[z * 128 + tid];
    const int p0 = blockIdx.x * 64, n0 = blockIdx.y * 64;
    const int rowS = tid >> 3, cS = (tid & 7) * 8;   // staging coords
    const int tx = tid & 15, ty = tid >> 4;          // p = tx*4, n = ty*4

    floatx2 acc[4][2];
    const floatx2 z2 = {0.f, 0.f};
    #pragma unroll
    for (int j = 0; j < 4; ++j) { acc[j][0] = z2; acc[j][1] = z2; }

    const int abase = z * 128;

    // prefetch chunk 0 into registers
    const float* up0 = &uT[(size_t)(abase + rowS) * NN + p0 + cS];
    const size_t vidx0 = (size_t)(abase + rowS) * NN + n0 + cS;
    float4 f0 = *(const float4*)up0;
    float4 f1 = *(const float4*)(up0 + 4);
    float4 g0 = *(const float4*)&v1T[vidx0];
    float4 g1 = *(const float4*)&v1T[vidx0 + 4];
    float4 h0 = *(const float4*)&v2T[vidx0];
    float4 h1 = *(const float4*)&v2T[vidx0 + 4];

    for (int ac = 0; ac < 128; ac += 32) {
        const int buf = (ac >> 5) & 1;
        // store staged registers (v1+v2 summed in-register)
        *(float4*)&us[buf][rowS][cS]     = f0;
        *(float4*)&us[buf][rowS][cS + 4] = f1;
        float4 s0, s1;
        s0.x = g0.x + h0.x; s0.y = g0.y + h0.y; s0.z = g0.z + h0.z; s0.w = g0.w + h0.w;
        s1.x = g1.x + h1.x; s1.y = g1.y + h1.y; s1.z = g1.z + h1.z; s1.w = g1.w + h1.w;
        *(float4*)&vs[buf][rowS][cS]     = s0;
        *(float4*)&vs[buf][rowS][cS + 4] = s1;
        __syncthreads();
        if (ac + 32 < 128) {
            const float* upn = &uT[(size_t)(abase + ac + 32 + rowS) * NN + p0 + cS];
            const size_t vn = (size_t)(abase + ac + 32 + rowS) * NN + n0 + cS;
            f0 = *(const float4*)upn;
            f1 = *(const float4*)(upn + 4);
            g0 = *(const float4*)&v1T[vn];
            g1 = *(const float4*)&v1T[vn + 4];
            h0 = *(const float4*)&v2T[vn];
            h1 = *(const float4*)&v2T[vn + 4];
        }
        #pragma unroll
        for (int a4 = 0; a4 < 32; a4 += 4) {
            float4 w4 = *(const float4*)&wfs[ac + a4];
            #pragma unroll
            for (int aa = 0; aa < 4; ++aa) {
                const int a = a4 + aa;
                float4 u4 = *(const float4*)&us[buf][a][tx * 4];
                float4 v4 = *(const float4*)&vs[buf][a][ty * 4];
                const float w = (aa == 0) ? w4.x : (aa == 1) ? w4.y : (aa == 2) ? w4.z : w4.w;
                floatx2 ulo = {u4.x, u4.y}, uhi = {u4.z, u4.w};
                const float vv[4] = {v4.x, v4.y, v4.z, v4.w};
                #pragma unroll
                for (int j = 0; j < 4; ++j) {
                    floatx2 t0 = ulo + vv[j];
                    floatx2 t1 = uhi + vv[j];
                    t0 = __builtin_elementwise_max(t0, z2);
                    t1 = __builtin_elementwise_max(t1, z2);
                    acc[j][0] = t0 * w + acc[j][0];
                    acc[j][1] = t1 * w + acc[j][1];
                }
            }
        }
        // no trailing barrier: dbuf + barrier(c+1) provide the fence
    }

    float* outp = att_part + (size_t)z * NN * PP;
    #pragma unroll
    for (int j = 0; j < 4; ++j) {
        float4 o;
        o.x = acc[j][0].x; o.y = acc[j][0].y; o.z = acc[j][1].x; o.w = acc[j][1].y;
        *(float4*)&outp[(size_t)(n0 + ty * 4 + j) * PP + p0 + tx * 4] = o;
    }
}

// ---------------------------------------------------------------------------
// Kernel 3: softmax over p of (att_part0 + att_part1); writes fp32 alpha to
// d_out AND bf16 alpha to ws for mfma_awe.  Wave-per-row, no barriers.
// ---------------------------------------------------------------------------
__global__ __launch_bounds__(256) void softmax_rows(
    const float* __restrict__ att_part, float* __restrict__ alpha,
    unsigned short* __restrict__ alpha_bf)
{
    const int wv = threadIdx.x >> 6, lane = threadIdx.x & 63;
    const int n = blockIdx.x * 4 + wv;
    const float* r0 = att_part + (size_t)n * PP;
    const float* r1 = att_part + (size_t)NN * PP + (size_t)n * PP;

    float4 x[4];
    #pragma unroll
    for (int i = 0; i < 4; ++i) {
        float4 a = *(const float4*)&r0[i * 256 + lane * 4];
        float4 b = *(const float4*)&r1[i * 256 + lane * 4];
        x[i].x = a.x + b.x; x[i].y = a.y + b.y; x[i].z = a.z + b.z; x[i].w = a.w + b.w;
    }

    float m = -1e30f;
    #pragma unroll
    for (int i = 0; i < 4; ++i)
        m = fmaxf(m, fmaxf(fmaxf(x[i].x, x[i].y), fmaxf(x[i].z, x[i].w)));
    #pragma unroll
    for (int off = 32; off > 0; off >>= 1) m = fmaxf(m, __shfl_xor(m, off, 64));

    float s = 0.f;
    #pragma unroll
    for (int i = 0; i < 4; ++i) {
        x[i].x = __expf(x[i].x - m); x[i].y = __expf(x[i].y - m);
        x[i].z = __expf(x[i].z - m); x[i].w = __expf(x[i].w - m);
        s += x[i].x + x[i].y + x[i].z + x[i].w;
    }
    #pragma unroll
    for (int off = 32; off > 0; off >>= 1) s += __shfl_xor(s, off, 64);
    const float inv = 1.0f / s;

    float* ar = alpha + (size_t)n * PP;
    unsigned short* br = alpha_bf + (size_t)n * PP;
    #pragma unroll
    for (int i = 0; i < 4; ++i) {
        x[i].x *= inv; x[i].y *= inv; x[i].z *= inv; x[i].w *= inv;
        *(float4*)&ar[i * 256 + lane * 4] = x[i];
        uint2 pk;
        pk.x = cvt_pk(x[i].x, x[i].y);
        pk.y = cvt_pk(x[i].z, x[i].w);
        *(uint2*)&br[i * 256 + lane * 4] = pk;
    }
}

// ---------------------------------------------------------------------------
// Kernel 4: awe = alpha @ E, both operands pre-converted bf16 (alpha_bf, ET).
// Tile 32m x 64n, BK=128 (8 K-steps, ONE barrier each), dbuf LDS (48 KB),
// 256 blocks, pure copy staging.
// ---------------------------------------------------------------------------
__global__ __launch_bounds__(256) void mfma_awe(
    const unsigned short* __restrict__ alpha_bf,
    const unsigned short* __restrict__ ET, float* __restrict__ awe)
{
    __shared__ __align__(16) unsigned short As[2][32 * 128];
    __shared__ __align__(16) unsigned short Bs[2][64 * 128];
    const int tid = threadIdx.x;
    const int K = PP;
    const int m0 = blockIdx.y * 32, n0 = blockIdx.x * 64;
    const int wv = tid >> 6, lm = tid & 15, lq = (tid >> 4) & 3;
    const int mw = (wv & 1) * 16, nw = (wv >> 1) * 32;
    int aoffs[4], b0offs[4], b1offs[4];
    #pragma unroll
    for (int ks = 0; ks < 4; ++ks) {
        aoffs[ks]  = t128_off(mw + lm,      lq * 8 + ks * 32);
        b0offs[ks] = t128_off(nw + lm,      lq * 8 + ks * 32);
        b1offs[ks] = t128_off(nw + 16 + lm, lq * 8 + ks * 32);
    }

    const int rowA = tid >> 3, kcA = (tid & 7) * 8;   // two uint4 per thread
    const int rowB = tid >> 2, kcB = (tid & 3) * 8;   // four uint4 per thread
    const int aoff0 = t128_off(rowA, kcA);
    const int aoff1 = t128_off(rowA, kcA + 64);
    int boffs[4];
    #pragma unroll
    for (int j = 0; j < 4; ++j) boffs[j] = t128_off(rowB, kcB + j * 32);
    const unsigned short* Ap = alpha_bf + (size_t)(m0 + rowA) * PP + kcA;
    const unsigned short* Bp = ET + (size_t)(n0 + rowB) * PP + kcB;

    floatx4 acc[2];
    const floatx4 zero = {0.f, 0.f, 0.f, 0.f};
    acc[0] = zero; acc[1] = zero;

    uint4 pa0 = *(const uint4*)Ap;
    uint4 pa1 = *(const uint4*)(Ap + 64);
    uint4 pb[4];
    #pragma unroll
    for (int j = 0; j < 4; ++j) pb[j] = *(const uint4*)(Bp + j * 32);

    for (int k0 = 0; k0 < K; k0 += 128) {
        const int buf = (k0 >> 7) & 1;
        *(uint4*)&As[buf][aoff0] = pa0;
        *(uint4*)&As[buf][aoff1] = pa1;
        #pragma unroll
        for (int j = 0; j < 4; ++j) *(uint4*)&Bs[buf][boffs[j]] = pb[j];
        __syncthreads();
        if (k0 + 128 < K) {
            pa0 = *(const uint4*)(Ap + k0 + 128);
            pa1 = *(const uint4*)(Ap + k0 + 192);
            #pragma unroll
            for (int j = 0; j < 4; ++j) pb[j] = *(const uint4*)(Bp + k0 + 128 + j * 32);
        }
        #pragma unroll
        for (int ks = 0; ks < 4; ++ks) {
            LdsVec fa, fb0, fb1;
            fa.u  = *(const uint4*)&As[buf][aoffs[ks]];
            fb0.u = *(const uint4*)&Bs[buf][b0offs[ks]];
            fb1.u = *(const uint4*)&Bs[buf][b1offs[ks]];
            acc[0] = __builtin_amdgcn_mfma_f32_16x16x32_bf16(fa.v, fb0.v, acc[0], 0, 0, 0);
            acc[1] = __builtin_amdgcn_mfma_f32_16x16x32_bf16(fa.v, fb1.v, acc[1], 0, 0, 0);
        }
        // no trailing barrier: dbuf + next iteration's barrier fence the hazard
    }

    #pragma unroll
    for (int s = 0; s < 2; ++s) {
        const int col = n0 + nw + s * 16 + lm;
        #pragma unroll
        for (int r = 0; r < 4; ++r)
            awe[(size_t)(m0 + mw + lq * 4 + r) * ENC + col] = acc[s][r];
    }
}

// ---------------------------------------------------------------------------
extern "C" void kernel_launch(void* const* d_in, const int* in_sizes, int n_in,
                              void* d_out, int out_size, void* d_ws, size_t ws_size,
                              hipStream_t stream)
{
    const float* encoder = (const float*)d_in[0];
    const float* dec     = (const float*)d_in[1];
    const float* lang    = (const float*)d_in[2];
    const float* We      = (const float*)d_in[3];
    const float* be      = (const float*)d_in[4];
    const float* Wt      = (const float*)d_in[5];
    const float* bt      = (const float*)d_in[6];
    const float* Wl      = (const float*)d_in[7];
    const float* bl      = (const float*)d_in[8];
    const float* Wf      = (const float*)d_in[9];
    // d_in[10] = bf: uniform over p -> cancels in softmax.

    float* uT   = (float*)d_ws;                  // [256][1024]
    float* v1T  = uT  + ATT * NN;                // [256][1024]
    float* v2T  = v1T + ATT * NN;                // [256][1024]
    float* attp = v2T + ATT * NN;                // [2][1024][1024]
    unsigned short* alpha_bf = (unsigned short*)(attp + 2 * (size_t)NN * PP);  // [1024][1024]
    unsigned short* ET       = alpha_bf + (size_t)NN * PP;                     // [512][1024]

    float* awe   = (float*)d_out;                // (1024, 512)
    float* alpha = (float*)d_out + NN * ENC;     // (1024, 1024)

    mfma_uv<<<dim3(4, 16, 4), 256, 0, stream>>>(
        encoder, We, be, dec, Wt, bt, lang, Wl, bl, uT, v1T, v2T, ET);
    att_fused<<<dim3(PP / 64, NN / 64, 2), 256, 0, stream>>>(uT, v1T, v2T, Wf, attp);
    softmax_rows<<<dim3(NN / 4), 256, 0, stream>>>(attp, alpha, alpha_bf);
    mfma_awe<<<dim3(ENC / 64, NN / 32), 256, 0, stream>>>(alpha_bf, ET, awe);
}

// Round 9
// 116.269 us; speedup vs baseline: 1.0596x; 1.0051x over previous
//
#include <hip/hip_runtime.h>
#include <hip/hip_bf16.h>
#include <math.h>

#define ENC 512
#define ATT 256
#define NN 1024
#define PP 1024

typedef __attribute__((ext_vector_type(8))) __bf16 bf16x8;
typedef __attribute__((ext_vector_type(4))) float floatx4;
typedef __attribute__((ext_vector_type(2))) float floatx2;

union LdsVec { uint4 u; bf16x8 v; };

// packed fp32->bf16 RNE via v_cvt_pk_bf16_f32 (gfx950)
__device__ __forceinline__ unsigned cvt_pk(float lo, float hi) {
    union { __hip_bfloat162 h; unsigned u; } x;
    x.h = __float22bfloat162_rn(float2{lo, hi});
    return x.u;
}
__device__ __forceinline__ uint4 cvt8(float4 f0, float4 f1) {
    uint4 r;
    r.x = cvt_pk(f0.x, f0.y); r.y = cvt_pk(f0.z, f0.w);
    r.z = cvt_pk(f1.x, f1.y); r.w = cvt_pk(f1.z, f1.w);
    return r;
}

// LDS tile, 256-k row stride bf16 (512B/row); 16B granules XOR-swizzled by
// row&7 within each 8-granule group -> fragment reads (lanes 0-15 = rows,
// fixed k-granule) spread across all 32 banks, <=2-way (free per m136).
__device__ __forceinline__ int t256_off(int row, int k) {
    const int g = k >> 3;
    return row * 256 + (((g & 24) | ((g ^ row) & 7)) << 3) + (k & 7);
}

// ---------------------------------------------------------------------------
// Kernel 1 (grid 4 x 16 x 4):
//  z=0: uT  = (E@We^T+be)^T   z=1: v1T = (D@Wt^T+bt)^T  z=2: v2T = (L@Wl^T+bl)^T
//    outputs TRANSPOSED [a=256][m=1024] so att_fused can stage without scatter.
//  z=3: ET = bf16 transpose of encoder (E^T [512][1024]) for mfma_awe.
// GEMM: 64x64 tile, BK=256 (2 K-steps, ONE barrier each), dbuf LDS (128 KB).
// Grid is 256 blocks = 1/CU, so the LDS growth costs no occupancy.
// ---------------------------------------------------------------------------
__global__ __launch_bounds__(256) void mfma_uv(
    const float* __restrict__ E,  const float* __restrict__ We, const float* __restrict__ be,
    const float* __restrict__ D,  const float* __restrict__ Wt, const float* __restrict__ bt,
    const float* __restrict__ Lg, const float* __restrict__ Wl, const float* __restrict__ bl,
    float* __restrict__ uT, float* __restrict__ v1T, float* __restrict__ v2T,
    unsigned short* __restrict__ ET)
{
    const int tid = threadIdx.x;

    if (blockIdx.z == 3) {
        // ---- E^T bf16 producer: two 64x64 tiles per block ----
        __shared__ unsigned short T[64][72];           // [k][n], stride 72 u16
        const int k0 = blockIdx.y * 64;
        const int kr = tid >> 2, nc = (tid & 3) * 16;  // read coords
        const int nr = tid >> 2, kc = (tid & 3) * 16;  // write coords
        #pragma unroll
        for (int t = 0; t < 2; ++t) {
            const int n0 = (blockIdx.x * 2 + t) * 64;
            const float* ep = E + (size_t)(k0 + kr) * ENC + n0 + nc;
            float4 a = *(const float4*)(ep + 0),  b = *(const float4*)(ep + 4);
            float4 c = *(const float4*)(ep + 8),  d = *(const float4*)(ep + 12);
            if (t) __syncthreads();                    // prior reads done
            *(uint4*)&T[kr][nc]     = cvt8(a, b);
            *(uint4*)&T[kr][nc + 8] = cvt8(c, d);
            __syncthreads();
            unsigned short tmp[16];
            #pragma unroll
            for (int i = 0; i < 16; ++i) tmp[i] = T[kc + i][nr];
            unsigned short* op = ET + (size_t)(n0 + nr) * PP + k0 + kc;
            *(uint4*)(op)     = *(uint4*)&tmp[0];
            *(uint4*)(op + 8) = *(uint4*)&tmp[8];
        }
        return;
    }

    __shared__ __align__(16) unsigned short As[2][64 * 256];
    __shared__ __align__(16) unsigned short Bs[2][64 * 256];
    const int K = 512;

    const float *A, *B, *bias; float* out;
    if      (blockIdx.z == 0) { A = E;  B = We; bias = be; out = uT;  }
    else if (blockIdx.z == 1) { A = D;  B = Wt; bias = bt; out = v1T; }
    else                      { A = Lg; B = Wl; bias = bl; out = v2T; }

    const int m0 = blockIdx.y * 64, n0 = blockIdx.x * 64;
    const int wv = tid >> 6, lm = tid & 15, lq = (tid >> 4) & 3;
    const int mb = (wv & 1) * 32, nb = (wv >> 1) * 32;
    int aoffs[2][8], boffs[2][8];
    #pragma unroll
    for (int ks = 0; ks < 8; ++ks) {
        aoffs[0][ks] = t256_off(mb + lm,      lq * 8 + ks * 32);
        aoffs[1][ks] = t256_off(mb + 16 + lm, lq * 8 + ks * 32);
        boffs[0][ks] = t256_off(nb + lm,      lq * 8 + ks * 32);
        boffs[1][ks] = t256_off(nb + 16 + lm, lq * 8 + ks * 32);
    }

    const int row = tid >> 2, kseg = (tid & 3) * 8;    // stage 8 granules/thread
    int soffs[8];
    #pragma unroll
    for (int j = 0; j < 8; ++j) soffs[j] = t256_off(row, kseg + j * 32);
    const float* Ap = A + (size_t)(m0 + row) * K + kseg;
    const float* Bp = B + (size_t)(n0 + row) * K + kseg;

    floatx4 acc[2][2];
    const floatx4 zero = {0.f, 0.f, 0.f, 0.f};
    acc[0][0] = zero; acc[0][1] = zero; acc[1][0] = zero; acc[1][1] = zero;

    float4 pa[16], pb[16];
    #pragma unroll
    for (int j = 0; j < 8; ++j) {
        pa[2 * j]     = *(const float4*)(Ap + j * 32);
        pa[2 * j + 1] = *(const float4*)(Ap + j * 32 + 4);
        pb[2 * j]     = *(const float4*)(Bp + j * 32);
        pb[2 * j + 1] = *(const float4*)(Bp + j * 32 + 4);
    }

    for (int k0 = 0; k0 < K; k0 += 256) {
        const int buf = (k0 >> 8) & 1;
        #pragma unroll
        for (int j = 0; j < 8; ++j) {
            *(uint4*)&As[buf][soffs[j]] = cvt8(pa[2 * j], pa[2 * j + 1]);
            *(uint4*)&Bs[buf][soffs[j]] = cvt8(pb[2 * j], pb[2 * j + 1]);
        }
        __syncthreads();
        if (k0 + 256 < K) {
            #pragma unroll
            for (int j = 0; j < 8; ++j) {
                pa[2 * j]     = *(const float4*)(Ap + k0 + 256 + j * 32);
                pa[2 * j + 1] = *(const float4*)(Ap + k0 + 256 + j * 32 + 4);
                pb[2 * j]     = *(const float4*)(Bp + k0 + 256 + j * 32);
                pb[2 * j + 1] = *(const float4*)(Bp + k0 + 256 + j * 32 + 4);
            }
        }
        #pragma unroll
        for (int ks = 0; ks < 8; ++ks) {
            LdsVec fa0, fa1, fb0, fb1;
            fa0.u = *(const uint4*)&As[buf][aoffs[0][ks]];
            fa1.u = *(const uint4*)&As[buf][aoffs[1][ks]];
            fb0.u = *(const uint4*)&Bs[buf][boffs[0][ks]];
            fb1.u = *(const uint4*)&Bs[buf][boffs[1][ks]];
            acc[0][0] = __builtin_amdgcn_mfma_f32_16x16x32_bf16(fa0.v, fb0.v, acc[0][0], 0, 0, 0);
            acc[0][1] = __builtin_amdgcn_mfma_f32_16x16x32_bf16(fa0.v, fb1.v, acc[0][1], 0, 0, 0);
            acc[1][0] = __builtin_amdgcn_mfma_f32_16x16x32_bf16(fa1.v, fb0.v, acc[1][0], 0, 0, 0);
            acc[1][1] = __builtin_amdgcn_mfma_f32_16x16x32_bf16(fa1.v, fb1.v, acc[1][1], 0, 0, 0);
        }
        // no trailing barrier: dbuf + next iteration's barrier fence the hazard
    }

    // transposed epilogue: out[a][m], float4 along m (r index)
    #pragma unroll
    for (int s = 0; s < 2; ++s) {
        const int col = n0 + nb + s * 16 + lm;          // a-dim
        const float bsum = bias[col];
        #pragma unroll
        for (int t = 0; t < 2; ++t) {
            const int mbase = m0 + mb + t * 16 + lq * 4;
            float4 o;
            o.x = acc[t][s][0] + bsum; o.y = acc[t][s][1] + bsum;
            o.z = acc[t][s][2] + bsum; o.w = acc[t][s][3] + bsum;
            *(float4*)&out[(size_t)col * NN + mbase] = o;
        }
    }
}

// ---------------------------------------------------------------------------
// Kernel 2: att[n,p] = sum_a relu(uT[a,p] + v1T[a,n] + v2T[a,n]) * Wf[a]
// Tile 64p x 64n, thread 4p x 4n. z splits a-range in half -> 512 blocks
// (2 blocks/CU); partials summed in softmax.
// Reg-prefetch + LDS dbuf, ONE barrier per chunk.
// ---------------------------------------------------------------------------
__global__ __launch_bounds__(256) void att_fused(
    const float* __restrict__ uT, const float* __restrict__ v1T,
    const float* __restrict__ v2T,
    const float* __restrict__ Wf, float* __restrict__ att_part)
{
    __shared__ float us[2][32][68];
    __shared__ float vs[2][32][68];
    __shared__ float wfs[128];
    const int tid = threadIdx.x;
    const int z = blockIdx.z;
    if (tid < 128) wfs[tid] = Wf[z * 128 + tid];
    const int p0 = blockIdx.x * 64, n0 = blockIdx.y * 64;
    const int rowS = tid >> 3, cS = (tid & 7) * 8;   // staging coords
    const int tx = tid & 15, ty = tid >> 4;          // p = tx*4, n = ty*4

    floatx2 acc[4][2];
    const floatx2 z2 = {0.f, 0.f};
    #pragma unroll
    for (int j = 0; j < 4; ++j) { acc[j][0] = z2; acc[j][1] = z2; }

    const int abase = z * 128;

    // prefetch chunk 0 into registers
    const float* up0 = &uT[(size_t)(abase + rowS) * NN + p0 + cS];
    const size_t vidx0 = (size_t)(abase + rowS) * NN + n0 + cS;
    float4 f0 = *(const float4*)up0;
    float4 f1 = *(const float4*)(up0 + 4);
    float4 g0 = *(const float4*)&v1T[vidx0];
    float4 g1 = *(const float4*)&v1T[vidx0 + 4];
    float4 h0 = *(const float4*)&v2T[vidx0];
    float4 h1 = *(const float4*)&v2T[vidx0 + 4];

    for (int ac = 0; ac < 128; ac += 32) {
        const int buf = (ac >> 5) & 1;
        // store staged registers (v1+v2 summed in-register)
        *(float4*)&us[buf][rowS][cS]     = f0;
        *(float4*)&us[buf][rowS][cS + 4] = f1;
        float4 s0, s1;
        s0.x = g0.x + h0.x; s0.y = g0.y + h0.y; s0.z = g0.z + h0.z; s0.w = g0.w + h0.w;
        s1.x = g1.x + h1.x; s1.y = g1.y + h1.y; s1.z = g1.z + h1.z; s1.w = g1.w + h1.w;
        *(float4*)&vs[buf][rowS][cS]     = s0;
        *(float4*)&vs[buf][rowS][cS + 4] = s1;
        __syncthreads();
        if (ac + 32 < 128) {
            const float* upn = &uT[(size_t)(abase + ac + 32 + rowS) * NN + p0 + cS];
            const size_t vn = (size_t)(abase + ac + 32 + rowS) * NN + n0 + cS;
            f0 = *(const float4*)upn;
            f1 = *(const float4*)(upn + 4);
            g0 = *(const float4*)&v1T[vn];
            g1 = *(const float4*)&v1T[vn + 4];
            h0 = *(const float4*)&v2T[vn];
            h1 = *(const float4*)&v2T[vn + 4];
        }
        #pragma unroll
        for (int a4 = 0; a4 < 32; a4 += 4) {
            float4 w4 = *(const float4*)&wfs[ac + a4];
            #pragma unroll
            for (int aa = 0; aa < 4; ++aa) {
                const int a = a4 + aa;
                float4 u4 = *(const float4*)&us[buf][a][tx * 4];
                float4 v4 = *(const float4*)&vs[buf][a][ty * 4];
                const float w = (aa == 0) ? w4.x : (aa == 1) ? w4.y : (aa == 2) ? w4.z : w4.w;
                floatx2 ulo = {u4.x, u4.y}, uhi = {u4.z, u4.w};
                const float vv[4] = {v4.x, v4.y, v4.z, v4.w};
                #pragma unroll
                for (int j = 0; j < 4; ++j) {
                    floatx2 t0 = ulo + vv[j];
                    floatx2 t1 = uhi + vv[j];
                    t0 = __builtin_elementwise_max(t0, z2);
                    t1 = __builtin_elementwise_max(t1, z2);
                    acc[j][0] = t0 * w + acc[j][0];
                    acc[j][1] = t1 * w + acc[j][1];
                }
            }
        }
        // no trailing barrier: dbuf + barrier(c+1) provide the fence
    }

    float* outp = att_part + (size_t)z * NN * PP;
    #pragma unroll
    for (int j = 0; j < 4; ++j) {
        float4 o;
        o.x = acc[j][0].x; o.y = acc[j][0].y; o.z = acc[j][1].x; o.w = acc[j][1].y;
        *(float4*)&outp[(size_t)(n0 + ty * 4 + j) * PP + p0 + tx * 4] = o;
    }
}

// ---------------------------------------------------------------------------
// Kernel 3: softmax over p of (att_part0 + att_part1); writes fp32 alpha to
// d_out AND bf16 alpha to ws for mfma_awe.  Wave-per-row, no barriers.
// ---------------------------------------------------------------------------
__global__ __launch_bounds__(256) void softmax_rows(
    const float* __restrict__ att_part, float* __restrict__ alpha,
    unsigned short* __restrict__ alpha_bf)
{
    const int wv = threadIdx.x >> 6, lane = threadIdx.x & 63;
    const int n = blockIdx.x * 4 + wv;
    const float* r0 = att_part + (size_t)n * PP;
    const float* r1 = att_part + (size_t)NN * PP + (size_t)n * PP;

    float4 x[4];
    #pragma unroll
    for (int i = 0; i < 4; ++i) {
        float4 a = *(const float4*)&r0[i * 256 + lane * 4];
        float4 b = *(const float4*)&r1[i * 256 + lane * 4];
        x[i].x = a.x + b.x; x[i].y = a.y + b.y; x[i].z = a.z + b.z; x[i].w = a.w + b.w;
    }

    float m = -1e30f;
    #pragma unroll
    for (int i = 0; i < 4; ++i)
        m = fmaxf(m, fmaxf(fmaxf(x[i].x, x[i].y), fmaxf(x[i].z, x[i].w)));
    #pragma unroll
    for (int off = 32; off > 0; off >>= 1) m = fmaxf(m, __shfl_xor(m, off, 64));

    float s = 0.f;
    #pragma unroll
    for (int i = 0; i < 4; ++i) {
        x[i].x = __expf(x[i].x - m); x[i].y = __expf(x[i].y - m);
        x[i].z = __expf(x[i].z - m); x[i].w = __expf(x[i].w - m);
        s += x[i].x + x[i].y + x[i].z + x[i].w;
    }
    #pragma unroll
    for (int off = 32; off > 0; off >>= 1) s += __shfl_xor(s, off, 64);
    const float inv = 1.0f / s;

    float* ar = alpha + (size_t)n * PP;
    unsigned short* br = alpha_bf + (size_t)n * PP;
    #pragma unroll
    for (int i = 0; i < 4; ++i) {
        x[i].x *= inv; x[i].y *= inv; x[i].z *= inv; x[i].w *= inv;
        *(float4*)&ar[i * 256 + lane * 4] = x[i];
        uint2 pk;
        pk.x = cvt_pk(x[i].x, x[i].y);
        pk.y = cvt_pk(x[i].z, x[i].w);
        *(uint2*)&br[i * 256 + lane * 4] = pk;
    }
}

// ---------------------------------------------------------------------------
// Kernel 4: awe = alpha @ E, both operands pre-converted bf16 (alpha_bf, ET).
// Tile 32m x 64n, BK=256 (4 K-steps, ONE barrier each), dbuf LDS (96 KB),
// 256 blocks (1/CU), pure copy staging.
// ---------------------------------------------------------------------------
__global__ __launch_bounds__(256) void mfma_awe(
    const unsigned short* __restrict__ alpha_bf,
    const unsigned short* __restrict__ ET, float* __restrict__ awe)
{
    __shared__ __align__(16) unsigned short As[2][32 * 256];
    __shared__ __align__(16) unsigned short Bs[2][64 * 256];
    const int tid = threadIdx.x;
    const int K = PP;
    const int m0 = blockIdx.y * 32, n0 = blockIdx.x * 64;
    const int wv = tid >> 6, lm = tid & 15, lq = (tid >> 4) & 3;
    const int mw = (wv & 1) * 16, nw = (wv >> 1) * 32;
    int aoffs[8], b0offs[8], b1offs[8];
    #pragma unroll
    for (int ks = 0; ks < 8; ++ks) {
        aoffs[ks]  = t256_off(mw + lm,      lq * 8 + ks * 32);
        b0offs[ks] = t256_off(nw + lm,      lq * 8 + ks * 32);
        b1offs[ks] = t256_off(nw + 16 + lm, lq * 8 + ks * 32);
    }

    const int rowA = tid >> 3, kcA = (tid & 7) * 8;   // 4 granules/thread (A)
    const int rowB = tid >> 2, kcB = (tid & 3) * 8;   // 8 granules/thread (B)
    int aoffsS[4], boffsS[8];
    #pragma unroll
    for (int j = 0; j < 4; ++j) aoffsS[j] = t256_off(rowA, kcA + j * 64);
    #pragma unroll
    for (int j = 0; j < 8; ++j) boffsS[j] = t256_off(rowB, kcB + j * 32);
    const unsigned short* Ap = alpha_bf + (size_t)(m0 + rowA) * PP + kcA;
    const unsigned short* Bp = ET + (size_t)(n0 + rowB) * PP + kcB;

    floatx4 acc[2];
    const floatx4 zero = {0.f, 0.f, 0.f, 0.f};
    acc[0] = zero; acc[1] = zero;

    uint4 pa[4], pb[8];
    #pragma unroll
    for (int j = 0; j < 4; ++j) pa[j] = *(const uint4*)(Ap + j * 64);
    #pragma unroll
    for (int j = 0; j < 8; ++j) pb[j] = *(const uint4*)(Bp + j * 32);

    for (int k0 = 0; k0 < K; k0 += 256) {
        const int buf = (k0 >> 8) & 1;
        #pragma unroll
        for (int j = 0; j < 4; ++j) *(uint4*)&As[buf][aoffsS[j]] = pa[j];
        #pragma unroll
        for (int j = 0; j < 8; ++j) *(uint4*)&Bs[buf][boffsS[j]] = pb[j];
        __syncthreads();
        if (k0 + 256 < K) {
            #pragma unroll
            for (int j = 0; j < 4; ++j) pa[j] = *(const uint4*)(Ap + k0 + 256 + j * 64);
            #pragma unroll
            for (int j = 0; j < 8; ++j) pb[j] = *(const uint4*)(Bp + k0 + 256 + j * 32);
        }
        #pragma unroll
        for (int ks = 0; ks < 8; ++ks) {
            LdsVec fa, fb0, fb1;
            fa.u  = *(const uint4*)&As[buf][aoffs[ks]];
            fb0.u = *(const uint4*)&Bs[buf][b0offs[ks]];
            fb1.u = *(const uint4*)&Bs[buf][b1offs[ks]];
            acc[0] = __builtin_amdgcn_mfma_f32_16x16x32_bf16(fa.v, fb0.v, acc[0], 0, 0, 0);
            acc[1] = __builtin_amdgcn_mfma_f32_16x16x32_bf16(fa.v, fb1.v, acc[1], 0, 0, 0);
        }
        // no trailing barrier: dbuf + next iteration's barrier fence the hazard
    }

    #pragma unroll
    for (int s = 0; s < 2; ++s) {
        const int col = n0 + nw + s * 16 + lm;
        #pragma unroll
        for (int r = 0; r < 4; ++r)
            awe[(size_t)(m0 + mw + lq * 4 + r) * ENC + col] = acc[s][r];
    }
}

// ---------------------------------------------------------------------------
extern "C" void kernel_launch(void* const* d_in, const int* in_sizes, int n_in,
                              void* d_out, int out_size, void* d_ws, size_t ws_size,
                              hipStream_t stream)
{
    const float* encoder = (const float*)d_in[0];
    const float* dec     = (const float*)d_in[1];
    const float* lang    = (const float*)d_in[2];
    const float* We      = (const float*)d_in[3];
    const float* be      = (const float*)d_in[4];
    const float* Wt      = (const float*)d_in[5];
    const float* bt      = (const float*)d_in[6];
    const float* Wl      = (const float*)d_in[7];
    const float* bl      = (const float*)d_in[8];
    const float* Wf      = (const float*)d_in[9];
    // d_in[10] = bf: uniform over p -> cancels in softmax.

    float* uT   = (float*)d_ws;                  // [256][1024]
    float* v1T  = uT  + ATT * NN;                // [256][1024]
    float* v2T  = v1T + ATT * NN;                // [256][1024]
    float* attp = v2T + ATT * NN;                // [2][1024][1024]
    unsigned short* alpha_bf = (unsigned short*)(attp + 2 * (size_t)NN * PP);  // [1024][1024]
    unsigned short* ET       = alpha_bf + (size_t)NN * PP;                     // [512][1024]

    float* awe   = (float*)d_out;                // (1024, 512)
    float* alpha = (float*)d_out + NN * ENC;     // (1024, 1024)

    mfma_uv<<<dim3(4, 16, 4), 256, 0, stream>>>(
        encoder, We, be, dec, Wt, bt, lang, Wl, bl, uT, v1T, v2T, ET);
    att_fused<<<dim3(PP / 64, NN / 64, 2), 256, 0, stream>>>(uT, v1T, v2T, Wf, attp);
    softmax_rows<<<dim3(NN / 4), 256, 0, stream>>>(attp, alpha, alpha_bf);
    mfma_awe<<<dim3(ENC / 64, NN / 32), 256, 0, stream>>>(alpha_bf, ET, awe);
}